// Round 3
// baseline (57582.770 us; speedup 1.0000x reference)
//
#include <hip/hip_runtime.h>

#define V 32000
#define D 256
#define H 256
#define T 128
#define B 32
#define SOS 126
#define H2 512

#define NBLK 512
#define NTHR 256
#define SCOPE __HIP_MEMORY_SCOPE_AGENT
#define LDS_FLOATS 19456   // 512*36 x-slab + 1024 scratch = 77824 B
#define S0 18432           // scratch base (floats)

__device__ __forceinline__ float sigf(float x) { return 1.f / (1.f + __expf(-x)); }
__device__ __forceinline__ float ftanh(float x) {
    x = fminf(15.f, fmaxf(-15.f, x));
    float e = __expf(2.f * x);
    return (e - 1.f) / (e + 1.f);
}

// ---------------- two-level grid barrier: bar[0..15] group counters, bar[16] root, bar[17] gen
__device__ __forceinline__ void gbar(int* bar) {
    __syncthreads();
    if (threadIdx.x == 0) {
        int g = __hip_atomic_load(bar + 17, __ATOMIC_RELAXED, SCOPE);
        __threadfence();
        int grp = (int)(blockIdx.x >> 5);
        int a = __hip_atomic_fetch_add(bar + grp, 1, __ATOMIC_ACQ_REL, SCOPE);
        if (a == 31) {
            int r = __hip_atomic_fetch_add(bar + 16, 1, __ATOMIC_ACQ_REL, SCOPE);
            if (r == 15) {
                for (int i = 0; i < 17; ++i)
                    __hip_atomic_store(bar + i, 0, __ATOMIC_RELAXED, SCOPE);
                __hip_atomic_fetch_add(bar + 17, 1, __ATOMIC_RELEASE, SCOPE);
            }
        }
        unsigned guard = 0;
        while (__hip_atomic_load(bar + 17, __ATOMIC_RELAXED, SCOPE) == g) {
            __builtin_amdgcn_s_sleep(2);
            if (++guard > 800000000u) break;   // safety: garbage > hang
        }
        (void)__hip_atomic_load(bar + 17, __ATOMIC_ACQUIRE, SCOPE);
    }
    __syncthreads();
}

// ---------------- generic LDS-tiled transpose: dst[C][R] from src[R][C]
__global__ __launch_bounds__(256) void k_tr(const float* __restrict__ src,
                                            float* __restrict__ dst, int R, int C) {
    __shared__ float tle[32][33];
    int rb = blockIdx.x * 32, cb = blockIdx.y * 32;
    int lr = threadIdx.x & 31, lc = threadIdx.x >> 5;
#pragma unroll
    for (int i = 0; i < 32; i += 8) tle[lc + i][lr] = src[(size_t)(rb + lc + i) * C + cb + lr];
    __syncthreads();
#pragma unroll
    for (int i = 0; i < 32; i += 8) dst[(size_t)(cb + lc + i) * R + rb + lr] = tle[lr][lc + i];
}

// ---------------- WencT[k][dir*1024 + u*4+g]
__global__ __launch_bounds__(256) void k_prep_encw(
    const float* __restrict__ Wih_f, const float* __restrict__ Whh_f,
    const float* __restrict__ Wih_b, const float* __restrict__ Whh_b,
    float* __restrict__ WencT) {
    int idx = blockIdx.x * 256 + threadIdx.x;     // 512*2048
    int k = idx >> 11, col = idx & 2047;
    int dir = col >> 10, cu = col & 1023;
    int u = cu >> 2, g = cu & 3;
    const float* Wih = dir ? Wih_b : Wih_f;
    const float* Whh = dir ? Whh_b : Whh_f;
    float v = (k < 256) ? Wih[(g * H + u) * D + k] : Whh[(g * H + u) * H + (k - 256)];
    WencT[idx] = v;
}

// ---------------- WdT[k][u*4+g]
__global__ __launch_bounds__(256) void k_prep_decw(const float* __restrict__ Wih_d,
                                                   const float* __restrict__ Whh_d,
                                                   float* __restrict__ WdT) {
    int idx = blockIdx.x * 256 + threadIdx.x;     // 1280*2048
    int k = idx >> 11, col = idx & 2047;
    int u = col >> 2, g = col & 3;
    float v = (k < 768) ? Wih_d[(size_t)(g * H2 + u) * 768 + k]
                        : Whh_d[(size_t)(g * H2 + u) * H2 + (k - 768)];
    WdT[idx] = v;
}

// ---------------- final: out = logits - lse[b*T+t]
__global__ __launch_bounds__(256) void k_norm(float* __restrict__ out,
                                              const float* __restrict__ lse) {
    const int total4 = B * T * V / 4;
    int stride = gridDim.x * 256;
    for (int i4 = blockIdx.x * 256 + threadIdx.x; i4 < total4; i4 += stride) {
        int rowv = i4 / (V / 4);
        float l = lse[rowv];
        float4* p = (float4*)out + i4;
        float4 v = *p;
        v.x -= l; v.y -= l; v.z -= l; v.w -= l;
        *p = v;
    }
}

// ==================== THE PERSISTENT KERNEL ====================
__global__ __launch_bounds__(256, 2) void k_seq(
    const int* __restrict__ x, const float* __restrict__ emb_enc,
    const float* __restrict__ emb_dec,
    const float* __restrict__ bih_f, const float* __restrict__ bhh_f,
    const float* __restrict__ bih_b, const float* __restrict__ bhh_b,
    const float* __restrict__ bih_d, const float* __restrict__ bhh_d,
    const float* __restrict__ Wa_e, const float* __restrict__ Wa_h,
    const float* __restrict__ b_a, const float* __restrict__ v_a,
    const float* __restrict__ bout,
    const float* __restrict__ WencT, const float* __restrict__ WdT,
    const float* __restrict__ WoutT, const float* __restrict__ WahT,
    float* __restrict__ enc_out, float* __restrict__ proj_e,
    float* __restrict__ cencT, float* __restrict__ zpenc,
    float* __restrict__ hdecT, float* __restrict__ cdecT,
    float* __restrict__ xcatT, float* __restrict__ q_buf, float* __restrict__ zp,
    float* __restrict__ es_g, float* __restrict__ Pm, float* __restrict__ Ps,
    int* __restrict__ Pi, float* __restrict__ lse, float* __restrict__ out,
    int* bar) {
    extern __shared__ float xs[];
    const int blk = blockIdx.x, tid = threadIdx.x;
    // lane decomposition used by all mm phases: kc in bits[5:3] (in-wave shfl), rows coalesced
    const int kc = (tid >> 3) & 7;
    const int rp = (tid >> 6) * 8 + (tid & 7);   // 0..31

    // ===================== ENCODER =====================
    for (int t = 0; t <= T; ++t) {
        if (blk < 128) {
            int rowgrp = blk >> 2, c = (blk >> 1) & 1, bh = blk & 1;
            int dir = rowgrp >> 4;
            // ---- stage
            if (c == 0) {
                if (t < T) {
                    for (int i = tid; i < 4096; i += 256) {
                        int bb = i >> 8, k = i & 255;
                        int tok = x[(bh * 16 + bb) * T + t];
                        xs[k * 20 + bb] = emb_enc[tok * 256 + k];
                    }
                }
            } else {
                if (t == 0) {
                    for (int i = tid; i < 4096; i += 256) {
                        int u = i >> 4, bb = i & 15;
                        xs[u * 20 + bb] = 0.f;
                    }
                } else {
                    bool writer = (rowgrp & 15) == 0;
                    const float* zpp = zpenc + ((t - 1) & 1) * 131072;
                    int pr = t & 1;   // read cencT[pr], write cencT[pr^1]
                    for (int i = tid; i < 4096; i += 256) {
                        int u = i >> 4, bb = i & 15, bG = bh * 16 + bb;
                        int r = dir * 1024 + u * 4;
                        float z[4];
#pragma unroll
                        for (int g = 0; g < 4; ++g) {
                            float bias = (dir ? bih_b : bih_f)[g * 256 + u] +
                                         (dir ? bhh_b : bhh_f)[g * 256 + u];
                            z[g] = zpp[(size_t)(r + g) * 32 + bG] +
                                   zpp[(size_t)(2048 + r + g) * 32 + bG] + bias;
                        }
                        int ci = ((pr * 2 + dir) * 256 + u) * 32 + bG;
                        float cp = cencT[ci];
                        float c2 = sigf(z[1]) * cp + sigf(z[0]) * ftanh(z[2]);
                        float h2 = sigf(z[3]) * ftanh(c2);
                        xs[u * 20 + bb] = h2;
                        if (writer) {
                            cencT[(((pr ^ 1) * 2 + dir) * 256 + u) * 32 + bG] = c2;
                            enc_out[(size_t)(bG * T + (t - 1)) * H2 + dir * 256 + u] = h2;
                            if (t == T) {
                                hdecT[(dir * 256 + u) * 32 + bG] = h2;
                                cdecT[(dir * 256 + u) * 32 + bG] = c2;
                            }
                        }
                    }
                }
            }
            __syncthreads();
            // ---- mm -> zpenc[t&1][c]
            if (t < T) {
                int r0 = rowgrp * 64 + rp * 2;
                float a0[16], a1[16];
#pragma unroll
                for (int j = 0; j < 16; ++j) { a0[j] = 0.f; a1[j] = 0.f; }
#pragma unroll 4
                for (int j = 0; j < 32; ++j) {
                    int kl = kc + 8 * j;
                    float2 w = *(const float2*)(WencT + (size_t)(c * 256 + kl) * 2048 + r0);
                    const float* xp = xs + kl * 20;
#pragma unroll
                    for (int q = 0; q < 4; ++q) {
                        float4 xv = *(const float4*)(xp + q * 4);
                        a0[q*4+0] = fmaf(w.x, xv.x, a0[q*4+0]); a1[q*4+0] = fmaf(w.y, xv.x, a1[q*4+0]);
                        a0[q*4+1] = fmaf(w.x, xv.y, a0[q*4+1]); a1[q*4+1] = fmaf(w.y, xv.y, a1[q*4+1]);
                        a0[q*4+2] = fmaf(w.x, xv.z, a0[q*4+2]); a1[q*4+2] = fmaf(w.y, xv.z, a1[q*4+2]);
                        a0[q*4+3] = fmaf(w.x, xv.w, a0[q*4+3]); a1[q*4+3] = fmaf(w.y, xv.w, a1[q*4+3]);
                    }
                }
#pragma unroll
                for (int j = 0; j < 16; ++j) {
                    a0[j] += __shfl_xor(a0[j], 8); a0[j] += __shfl_xor(a0[j], 16); a0[j] += __shfl_xor(a0[j], 32);
                    a1[j] += __shfl_xor(a1[j], 8); a1[j] += __shfl_xor(a1[j], 16); a1[j] += __shfl_xor(a1[j], 32);
                }
                if (((tid >> 3) & 7) == 0) {
                    float* zb = zpenc + (t & 1) * 131072 + (size_t)(c * 2048 + r0) * 32 + bh * 16;
#pragma unroll
                    for (int q = 0; q < 4; ++q) {
                        *(float4*)(zb + q * 4)      = make_float4(a0[q*4], a0[q*4+1], a0[q*4+2], a0[q*4+3]);
                        *(float4*)(zb + 32 + q * 4) = make_float4(a1[q*4], a1[q*4+1], a1[q*4+2], a1[q*4+3]);
                    }
                }
            }
        }
        gbar(bar);
    }

    // ===================== pre-decoder: proj_e + q0 =====================
    {
        if (blk < 256) {
            // proj_e = enc_out @ Wa_e^T, 16 rows per block
            int r0 = blk * 16;
            for (int i = tid; i < 16 * 512; i += 256) {
                int r = i >> 9, k = i & 511;
                xs[r * 512 + k] = enc_out[(size_t)(r0 + r) * H2 + k];
            }
            __syncthreads();
            int j0 = tid * 2;
            float acc0[16], acc1[16];
#pragma unroll
            for (int r = 0; r < 16; ++r) { acc0[r] = 0.f; acc1[r] = 0.f; }
            const float* w0 = Wa_e + j0 * H2;
            const float* w1 = Wa_e + (j0 + 1) * H2;
            for (int k = 0; k < H2; k += 4) {
                float4 wa = *(const float4*)(w0 + k);
                float4 wb = *(const float4*)(w1 + k);
#pragma unroll
                for (int r = 0; r < 16; ++r) {
                    float4 xv = *(const float4*)(&xs[r * 512 + k]);
                    acc0[r] = fmaf(wa.x, xv.x, acc0[r]); acc0[r] = fmaf(wa.y, xv.y, acc0[r]);
                    acc0[r] = fmaf(wa.z, xv.z, acc0[r]); acc0[r] = fmaf(wa.w, xv.w, acc0[r]);
                    acc1[r] = fmaf(wb.x, xv.x, acc1[r]); acc1[r] = fmaf(wb.y, xv.y, acc1[r]);
                    acc1[r] = fmaf(wb.z, xv.z, acc1[r]); acc1[r] = fmaf(wb.w, xv.w, acc1[r]);
                }
            }
#pragma unroll
            for (int r = 0; r < 16; ++r) {
                float2 st; st.x = acc0[r]; st.y = acc1[r];
                *(float2*)(proj_e + (size_t)(r0 + r) * H2 + j0) = st;
            }
        } else if (blk < 320) {
            // q0[b][j] = h0 . Wa_h[j]
            int gi = (blk - 256) * 256 + tid;
            int j = gi >> 5, b = gi & 31;
            float a0 = 0, a1 = 0, a2 = 0, a3 = 0;
            const float* wr = Wa_h + (size_t)j * H2;
            for (int k = 0; k < H2; k += 4) {
                float4 w = *(const float4*)(wr + k);
                a0 = fmaf(w.x, hdecT[(k    ) * 32 + b], a0);
                a1 = fmaf(w.y, hdecT[(k + 1) * 32 + b], a1);
                a2 = fmaf(w.z, hdecT[(k + 2) * 32 + b], a2);
                a3 = fmaf(w.w, hdecT[(k + 3) * 32 + b], a3);
            }
            q_buf[b * H2 + j] = (a0 + a1) + (a2 + a3);
        }
    }
    gbar(bar);

    // ===================== DECODER =====================
    for (int t = 0; t < T; ++t) {
        // ---------- ph1: argmax finalize + emb (blocks 0..31) || energy (32..511)
        if (blk < 32) {
            int b = blk;
            float* rm = xs + S0; float* rs = rm + 256; int* ri = (int*)(rs + 256);
            int tok = SOS;
            if (t > 0) {
                float m = -INFINITY, s = 0.f; int mi = 0x7fffffff;
                for (int i = tid; i < 512; i += 256) {
                    if (i < 500) {
                        float m2 = Pm[b * 512 + i], s2 = Ps[b * 512 + i];
                        int i2 = Pi[b * 512 + i];
                        if (m2 > m)      { s = s2 + s * __expf(m - m2); m = m2; mi = i2; }
                        else if (m > m2) { s = s + s2 * __expf(m2 - m); }
                        else             { s = s + s2; mi = (mi < i2) ? mi : i2; }
                    }
                }
                rm[tid] = m; rs[tid] = s; ri[tid] = mi;
                __syncthreads();
                for (int off = 128; off >= 1; off >>= 1) {
                    if (tid < off) {
                        float m1 = rm[tid], m2 = rm[tid + off];
                        float s1 = rs[tid], s2 = rs[tid + off];
                        int i1 = ri[tid], i2 = ri[tid + off];
                        float m_, s_; int i_;
                        if (m2 > m1)      { m_ = m2; s_ = s2 + s1 * __expf(m1 - m2); i_ = i2; }
                        else if (m1 > m2) { m_ = m1; s_ = s1 + s2 * __expf(m2 - m1); i_ = i1; }
                        else              { m_ = m1; s_ = s1 + s2; i_ = (i1 < i2) ? i1 : i2; }
                        rm[tid] = m_; rs[tid] = s_; ri[tid] = i_;
                    }
                    __syncthreads();
                }
                if (tid == 0) lse[b * T + (t - 1)] = rm[0] + logf(rs[0]);
                __syncthreads();
                tok = ri[0];
            }
            xcatT[tid * 32 + b] = emb_dec[tok * 256 + tid];
        } else {
            // energy: tasks (b,tt) = 4096 over 1920 waves
            int w = (blk - 32) * 4 + (tid >> 6);
            int l = tid & 63;
            float4 ba0 = *(const float4*)(b_a + l * 8);
            float4 ba1 = *(const float4*)(b_a + l * 8 + 4);
            float4 va0 = *(const float4*)(v_a + l * 8);
            float4 va1 = *(const float4*)(v_a + l * 8 + 4);
            for (int task = w; task < 4096; task += 1920) {
                int b = task >> 7, tt = task & 127;
                float4 q0 = *(const float4*)(q_buf + b * H2 + l * 8);
                float4 q1 = *(const float4*)(q_buf + b * H2 + l * 8 + 4);
                const float* pp = proj_e + (size_t)(b * T + tt) * H2 + l * 8;
                float4 p0 = *(const float4*)(pp);
                float4 p1 = *(const float4*)(pp + 4);
                float s = ftanh(p0.x + q0.x + ba0.x) * va0.x + ftanh(p0.y + q0.y + ba0.y) * va0.y
                        + ftanh(p0.z + q0.z + ba0.z) * va0.z + ftanh(p0.w + q0.w + ba0.w) * va0.w
                        + ftanh(p1.x + q1.x + ba1.x) * va1.x + ftanh(p1.y + q1.y + ba1.y) * va1.y
                        + ftanh(p1.z + q1.z + ba1.z) * va1.z + ftanh(p1.w + q1.w + ba1.w) * va1.w;
#pragma unroll
                for (int off = 32; off >= 1; off >>= 1) s += __shfl_xor(s, off);
                if (l == 0) es_g[b * 128 + tt] = s;
            }
        }
        gbar(bar);

        // ---------- ph2: softmax + ctx (0..31) || B-h: Whh x h_{t-1} (64..191)
        if (blk < 32) {
            int b = blk;
            float* es = xs + S0; float* red = es + 128; float* wsm = red + 128;
            if (tid < 128) { es[tid] = es_g[b * 128 + tid]; red[tid] = es[tid]; }
            __syncthreads();
            for (int off = 64; off >= 1; off >>= 1) {
                if (tid < off) red[tid] = fmaxf(red[tid], red[tid + off]);
                __syncthreads();
            }
            float M = red[0];
            __syncthreads();
            float ev = 0.f;
            if (tid < 128) { ev = __expf(es[tid] - M); red[tid] = ev; }
            __syncthreads();
            for (int off = 64; off >= 1; off >>= 1) {
                if (tid < off) red[tid] += red[tid + off];
                __syncthreads();
            }
            float S = red[0];
            __syncthreads();
            if (tid < 128) wsm[tid] = ev / S;
            __syncthreads();
            // ctx: kk = tid, tid+256
            float acc0 = 0.f, acc1 = 0.f;
            const float* eo = enc_out + (size_t)b * T * H2;
#pragma unroll 8
            for (int t2 = 0; t2 < T; ++t2) {
                float wv = wsm[t2];
                acc0 = fmaf(wv, eo[t2 * H2 + tid], acc0);
                acc1 = fmaf(wv, eo[t2 * H2 + tid + 256], acc1);
            }
            xcatT[(256 + tid) * 32 + b] = acc0;
            xcatT[(512 + tid) * 32 + b] = acc1;
        } else if (blk >= 64 && blk < 192) {
            int idx = blk - 64;
            int rowgrp = idx >> 2, ch = (idx >> 1) & 1, bh = idx & 1;
            // stage h chunk [ch*256,+256) b-half into xs[256][20]
            const float* src = hdecT + (size_t)ch * 256 * 32;
            for (int i4 = tid; i4 < 1024; i4 += 256) {
                int k = i4 >> 2, b4 = (i4 & 3) * 4;
                *(float4*)(xs + k * 20 + b4) = *(const float4*)(src + k * 32 + bh * 16 + b4);
            }
            __syncthreads();
            int r0 = rowgrp * 64 + rp * 2;
            int kOFF = 768 + ch * 256;
            float a0[16], a1[16];
#pragma unroll
            for (int j = 0; j < 16; ++j) { a0[j] = 0.f; a1[j] = 0.f; }
#pragma unroll 4
            for (int j = 0; j < 32; ++j) {
                int kl = kc + 8 * j;
                float2 w = *(const float2*)(WdT + (size_t)(kOFF + kl) * 2048 + r0);
                const float* xp = xs + kl * 20;
#pragma unroll
                for (int q = 0; q < 4; ++q) {
                    float4 xv = *(const float4*)(xp + q * 4);
                    a0[q*4+0] = fmaf(w.x, xv.x, a0[q*4+0]); a1[q*4+0] = fmaf(w.y, xv.x, a1[q*4+0]);
                    a0[q*4+1] = fmaf(w.x, xv.y, a0[q*4+1]); a1[q*4+1] = fmaf(w.y, xv.y, a1[q*4+1]);
                    a0[q*4+2] = fmaf(w.x, xv.z, a0[q*4+2]); a1[q*4+2] = fmaf(w.y, xv.z, a1[q*4+2]);
                    a0[q*4+3] = fmaf(w.x, xv.w, a0[q*4+3]); a1[q*4+3] = fmaf(w.y, xv.w, a1[q*4+3]);
                }
            }
#pragma unroll
            for (int j = 0; j < 16; ++j) {
                a0[j] += __shfl_xor(a0[j], 8); a0[j] += __shfl_xor(a0[j], 16); a0[j] += __shfl_xor(a0[j], 32);
                a1[j] += __shfl_xor(a1[j], 8); a1[j] += __shfl_xor(a1[j], 16); a1[j] += __shfl_xor(a1[j], 32);
            }
            if (((tid >> 3) & 7) == 0) {
                float* zb = zp + (size_t)((3 + ch) * 2048 + r0) * 32 + bh * 16;
#pragma unroll
                for (int q = 0; q < 4; ++q) {
                    *(float4*)(zb + q * 4)      = make_float4(a0[q*4], a0[q*4+1], a0[q*4+2], a0[q*4+3]);
                    *(float4*)(zb + 32 + q * 4) = make_float4(a1[q*4], a1[q*4+1], a1[q*4+2], a1[q*4+3]);
                }
            }
        }
        gbar(bar);

        // ---------- ph3: B-x: Wih x xcat[0:768) (blocks 0..191)
        if (blk < 192) {
            int rowgrp = blk / 6, rem = blk % 6;
            int ch = rem >> 1, bh = rem & 1;
            const float* src = xcatT + (size_t)ch * 256 * 32;
            for (int i4 = tid; i4 < 1024; i4 += 256) {
                int k = i4 >> 2, b4 = (i4 & 3) * 4;
                *(float4*)(xs + k * 20 + b4) = *(const float4*)(src + k * 32 + bh * 16 + b4);
            }
            __syncthreads();
            int r0 = rowgrp * 64 + rp * 2;
            int kOFF = ch * 256;
            float a0[16], a1[16];
#pragma unroll
            for (int j = 0; j < 16; ++j) { a0[j] = 0.f; a1[j] = 0.f; }
#pragma unroll 4
            for (int j = 0; j < 32; ++j) {
                int kl = kc + 8 * j;
                float2 w = *(const float2*)(WdT + (size_t)(kOFF + kl) * 2048 + r0);
                const float* xp = xs + kl * 20;
#pragma unroll
                for (int q = 0; q < 4; ++q) {
                    float4 xv = *(const float4*)(xp + q * 4);
                    a0[q*4+0] = fmaf(w.x, xv.x, a0[q*4+0]); a1[q*4+0] = fmaf(w.y, xv.x, a1[q*4+0]);
                    a0[q*4+1] = fmaf(w.x, xv.y, a0[q*4+1]); a1[q*4+1] = fmaf(w.y, xv.y, a1[q*4+1]);
                    a0[q*4+2] = fmaf(w.x, xv.z, a0[q*4+2]); a1[q*4+2] = fmaf(w.y, xv.z, a1[q*4+2]);
                    a0[q*4+3] = fmaf(w.x, xv.w, a0[q*4+3]); a1[q*4+3] = fmaf(w.y, xv.w, a1[q*4+3]);
                }
            }
#pragma unroll
            for (int j = 0; j < 16; ++j) {
                a0[j] += __shfl_xor(a0[j], 8); a0[j] += __shfl_xor(a0[j], 16); a0[j] += __shfl_xor(a0[j], 32);
                a1[j] += __shfl_xor(a1[j], 8); a1[j] += __shfl_xor(a1[j], 16); a1[j] += __shfl_xor(a1[j], 32);
            }
            if (((tid >> 3) & 7) == 0) {
                float* zb = zp + (size_t)(ch * 2048 + r0) * 32 + bh * 16;
#pragma unroll
                for (int q = 0; q < 4; ++q) {
                    *(float4*)(zb + q * 4)      = make_float4(a0[q*4], a0[q*4+1], a0[q*4+2], a0[q*4+3]);
                    *(float4*)(zb + 32 + q * 4) = make_float4(a1[q*4], a1[q*4+1], a1[q*4+2], a1[q*4+3]);
                }
            }
        }
        gbar(bar);

        // ---------- ph3b: cell (blocks 0..63)
        if (blk < 64) {
            int i = blk * 256 + tid;
            int u = i >> 5, b = i & 31;
            float z[4];
#pragma unroll
            for (int g = 0; g < 4; ++g) {
                float s = bih_d[g * H2 + u] + bhh_d[g * H2 + u];
#pragma unroll
                for (int c = 0; c < 5; ++c) s += zp[(size_t)(c * 2048 + u * 4 + g) * 32 + b];
                z[g] = s;
            }
            float cp = cdecT[u * 32 + b];
            float c2 = sigf(z[1]) * cp + sigf(z[0]) * ftanh(z[2]);
            cdecT[u * 32 + b] = c2;
            hdecT[u * 32 + b] = sigf(z[3]) * ftanh(c2);
        }
        gbar(bar);

        // ---------- ph4: logits (blocks 0..499) + q piggyback (500..507)
        if (blk < 508) {
            // stage h [512][36-padded]
            for (int i4 = tid; i4 < 4096; i4 += 256) {
                int k = i4 >> 3, b4 = (i4 & 7) * 4;
                *(float4*)(xs + k * 36 + b4) = *(const float4*)(hdecT + k * 32 + b4);
            }
            __syncthreads();
            bool isQ = (blk >= 500);
            const float* wb = isQ ? (WahT + (blk - 500) * 64) : (WoutT + blk * 64);
            const int wst = isQ ? H2 : V;
            int rp2 = rp * 2;
            float a0[32], a1[32];
#pragma unroll
            for (int j = 0; j < 32; ++j) { a0[j] = 0.f; a1[j] = 0.f; }
#pragma unroll 4
            for (int kk = 0; kk < 64; ++kk) {
                int k = kc + 8 * kk;
                float2 w = *(const float2*)(wb + (size_t)k * wst + rp2);
                const float* xp = xs + k * 36;
#pragma unroll
                for (int q = 0; q < 8; ++q) {
                    float4 xv = *(const float4*)(xp + q * 4);
                    a0[q*4+0] = fmaf(w.x, xv.x, a0[q*4+0]); a1[q*4+0] = fmaf(w.y, xv.x, a1[q*4+0]);
                    a0[q*4+1] = fmaf(w.x, xv.y, a0[q*4+1]); a1[q*4+1] = fmaf(w.y, xv.y, a1[q*4+1]);
                    a0[q*4+2] = fmaf(w.x, xv.z, a0[q*4+2]); a1[q*4+2] = fmaf(w.y, xv.z, a1[q*4+2]);
                    a0[q*4+3] = fmaf(w.x, xv.w, a0[q*4+3]); a1[q*4+3] = fmaf(w.y, xv.w, a1[q*4+3]);
                }
            }
#pragma unroll
            for (int j = 0; j < 32; ++j) {
                a0[j] += __shfl_xor(a0[j], 8); a0[j] += __shfl_xor(a0[j], 16); a0[j] += __shfl_xor(a0[j], 32);
                a1[j] += __shfl_xor(a1[j], 8); a1[j] += __shfl_xor(a1[j], 16); a1[j] += __shfl_xor(a1[j], 32);
            }
            __syncthreads();   // xs reads done; safe to alias z into xs
            if (!isQ) {
                if (((tid >> 3) & 7) == 0) {
#pragma unroll
                    for (int j = 0; j < 32; ++j) {
                        xs[(rp2    ) * 37 + j] = a0[j];
                        xs[(rp2 + 1) * 37 + j] = a1[j];
                    }
                }
                __syncthreads();
                int row0 = blk * 64;
                // coalesced stores: lane = row, 8 b's each
                {
                    int r = tid & 63, bo = tid >> 6;
                    float bv = bout[row0 + r];
#pragma unroll
                    for (int e = 0; e < 8; ++e) {
                        int b = bo * 8 + e;
                        out[((size_t)(b * T) + t) * V + row0 + r] = xs[r * 37 + b] + bv;
                    }
                }
                // per-block argmax/lse partials
                float* pm8 = xs + S0; float* ps8 = pm8 + 256; int* pi8 = (int*)(ps8 + 256);
                {
                    int g = tid >> 5, b = tid & 31;
                    float m = -INFINITY, s = 0.f; int mi = 0;
#pragma unroll
                    for (int i = 0; i < 8; ++i) {
                        int rr = g * 8 + i;
                        float v = xs[rr * 37 + b] + bout[row0 + rr];
                        if (v > m) { s *= __expf(m - v); m = v; mi = row0 + rr; }
                        s += __expf(v - m);
                    }
                    pm8[g * 32 + b] = m; ps8[g * 32 + b] = s; pi8[g * 32 + b] = mi;
                }
                __syncthreads();
                if (tid < 32) {
                    int b = tid;
                    float m = pm8[b], s = ps8[b]; int mi = pi8[b];
#pragma unroll
                    for (int g = 1; g < 8; ++g) {
                        float m2 = pm8[g * 32 + b], s2 = ps8[g * 32 + b]; int i2 = pi8[g * 32 + b];
                        if (m2 > m)      { s = s2 + s * __expf(m - m2); m = m2; mi = i2; }
                        else if (m > m2) { s = s + s2 * __expf(m2 - m); }
                        else             { s = s + s2; mi = (mi < i2) ? mi : i2; }
                    }
                    Pm[b * 512 + blk] = m; Ps[b * 512 + blk] = s; Pi[b * 512 + blk] = mi;
                }
            } else {
                if (((tid >> 3) & 7) == 0) {
                    int j0 = (blk - 500) * 64 + rp2;
#pragma unroll
                    for (int b = 0; b < 32; ++b) {
                        q_buf[b * H2 + j0]     = a0[b];
                        q_buf[b * H2 + j0 + 1] = a1[b];
                    }
                }
            }
        }
        gbar(bar);
    }

    // ---------- tail: lse for t = 127
    if (blk < 32) {
        int b = blk;
        float* rm = xs + S0; float* rs = rm + 256; int* ri = (int*)(rs + 256);
        float m = -INFINITY, s = 0.f; int mi = 0x7fffffff;
        for (int i = tid; i < 512; i += 256) {
            if (i < 500) {
                float m2 = Pm[b * 512 + i], s2 = Ps[b * 512 + i]; int i2 = Pi[b * 512 + i];
                if (m2 > m)      { s = s2 + s * __expf(m - m2); m = m2; mi = i2; }
                else if (m > m2) { s = s + s2 * __expf(m2 - m); }
                else             { s = s + s2; mi = (mi < i2) ? mi : i2; }
            }
        }
        rm[tid] = m; rs[tid] = s; ri[tid] = mi;
        __syncthreads();
        for (int off = 128; off >= 1; off >>= 1) {
            if (tid < off) {
                float m1 = rm[tid], m2 = rm[tid + off];
                float s1 = rs[tid], s2 = rs[tid + off];
                float m_, s_;
                if (m2 > m1)      { m_ = m2; s_ = s2 + s1 * __expf(m1 - m2); }
                else if (m1 > m2) { m_ = m1; s_ = s1 + s2 * __expf(m2 - m1); }
                else              { m_ = m1; s_ = s1 + s2; }
                rm[tid] = m_; rs[tid] = s_;
            }
            __syncthreads();
        }
        if (tid == 0) lse[b * T + (T - 1)] = rm[0] + logf(rs[0]);
    }
}

extern "C" void kernel_launch(void* const* d_in, const int* in_sizes, int n_in,
                              void* d_out, int out_size, void* d_ws, size_t ws_size,
                              hipStream_t stream) {
    const int* x          = (const int*)d_in[0];
    const float* emb_enc  = (const float*)d_in[1];
    const float* Wih_f    = (const float*)d_in[2];
    const float* Whh_f    = (const float*)d_in[3];
    const float* bih_f    = (const float*)d_in[4];
    const float* bhh_f    = (const float*)d_in[5];
    const float* Wih_b    = (const float*)d_in[6];
    const float* Whh_b    = (const float*)d_in[7];
    const float* bih_b    = (const float*)d_in[8];
    const float* bhh_b    = (const float*)d_in[9];
    const float* emb_dec  = (const float*)d_in[10];
    const float* Wa_h     = (const float*)d_in[11];
    const float* Wa_e     = (const float*)d_in[12];
    const float* v_a      = (const float*)d_in[13];
    const float* b_a      = (const float*)d_in[14];
    const float* Wih_d    = (const float*)d_in[15];
    const float* Whh_d    = (const float*)d_in[16];
    const float* bih_d    = (const float*)d_in[17];
    const float* bhh_d    = (const float*)d_in[18];
    const float* Wout     = (const float*)d_in[19];
    const float* bout     = (const float*)d_in[20];
    float* out = (float*)d_out;

    float* ws = (float*)d_ws;
    size_t o = 0;
    float* enc_out = ws + o; o += (size_t)B * T * H2;     // 2,097,152
    float* proj_e  = ws + o; o += (size_t)B * T * H2;     // 2,097,152
    float* WoutT   = ws + o; o += (size_t)H2 * V;         // 16,384,000
    float* WdT     = ws + o; o += (size_t)1280 * 2048;    // 2,621,440
    float* WencT   = ws + o; o += (size_t)512 * 2048;     // 1,048,576
    float* WahT    = ws + o; o += (size_t)H2 * H2;        // 262,144
    float* cencT   = ws + o; o += 2 * 2 * 256 * 32;       // 32,768
    float* zpenc   = ws + o; o += 2 * 2 * 2048 * 32;      // 262,144
    float* hdecT   = ws + o; o += 16384;
    float* cdecT   = ws + o; o += 16384;
    float* xcatT   = ws + o; o += 768 * 32;               // 24,576
    float* q_buf   = ws + o; o += 16384;
    float* zp      = ws + o; o += (size_t)5 * 2048 * 32;  // 327,680
    float* es_g    = ws + o; o += 32 * 128;
    float* Pm      = ws + o; o += 32 * 512;
    float* Ps      = ws + o; o += 32 * 512;
    float* lse     = ws + o; o += 32 * 128;
    int*   Pi      = (int*)(ws + o); o += 32 * 512;
    int*   bar     = (int*)(ws + o); o += 256;

    hipMemsetAsync(cencT, 0, 2 * 2 * 256 * 32 * sizeof(float), stream);
    hipMemsetAsync(bar, 0, 256 * sizeof(int), stream);

    k_tr<<<dim3(1000, 16), 256, 0, stream>>>(Wout, WoutT, V, H2);
    k_tr<<<dim3(16, 16), 256, 0, stream>>>(Wa_h, WahT, H2, H2);
    k_prep_encw<<<4096, 256, 0, stream>>>(Wih_f, Whh_f, Wih_b, Whh_b, WencT);
    k_prep_decw<<<10240, 256, 0, stream>>>(Wih_d, Whh_d, WdT);

    k_seq<<<NBLK, NTHR, LDS_FLOATS * sizeof(float), stream>>>(
        x, emb_enc, emb_dec,
        bih_f, bhh_f, bih_b, bhh_b, bih_d, bhh_d,
        Wa_e, Wa_h, b_a, v_a, bout,
        WencT, WdT, WoutT, WahT,
        enc_out, proj_e, cencT, zpenc,
        hdecT, cdecT, xcatT, q_buf, zp,
        es_g, Pm, Ps, Pi, lse, out, bar);

    k_norm<<<4096, 256, 0, stream>>>(out, lse);
}

// Round 4
// 21297.351 us; speedup vs baseline: 2.7038x; 2.7038x over previous
//
#include <hip/hip_runtime.h>

#define V 32000
#define D 256
#define H 256
#define T 128
#define B 32
#define SOS 126
#define H2 512

#define NBLK 512
#define NTHR 256
#define SCOPE __HIP_MEMORY_SCOPE_AGENT
#define LDS_FLOATS 19456   // 512*36 x-slab + 1024 scratch = 77824 B (2 blocks/CU)
#define S0 18432           // scratch base (floats)

__device__ __forceinline__ float sigf(float x) { return 1.f / (1.f + __expf(-x)); }
__device__ __forceinline__ float ftanh(float x) {
    x = fminf(15.f, fmaxf(-15.f, x));
    float e = __expf(2.f * x);
    return (e - 1.f) / (e + 1.f);
}

// ---------------- store-based grid barrier (no RMWs).
// slots: one int per block, 128B apart. master = block 0 sweeps and publishes gen.
__device__ __forceinline__ void gbar(int* __restrict__ slots, int* __restrict__ gen, int tgt) {
    __syncthreads();
    if (blockIdx.x == 0) {
        if (threadIdx.x == 0) {
            __builtin_amdgcn_fence(__ATOMIC_RELEASE, "agent");
            __hip_atomic_store(slots, tgt, __ATOMIC_RELAXED, SCOPE);
        }
        int i0 = (int)threadIdx.x * 2;
        unsigned guard = 0;
        while (__hip_atomic_load(slots + (size_t)i0 * 32, __ATOMIC_RELAXED, SCOPE) < tgt) {
            __builtin_amdgcn_s_sleep(1);
            if (++guard > 100000000u) break;   // safety: garbage > hang
        }
        guard = 0;
        while (__hip_atomic_load(slots + (size_t)(i0 + 1) * 32, __ATOMIC_RELAXED, SCOPE) < tgt) {
            __builtin_amdgcn_s_sleep(1);
            if (++guard > 100000000u) break;
        }
        __syncthreads();
        if (threadIdx.x == 0) {
            __builtin_amdgcn_fence(__ATOMIC_ACQUIRE, "agent");
            __builtin_amdgcn_fence(__ATOMIC_RELEASE, "agent");
            __hip_atomic_store(gen, tgt, __ATOMIC_RELAXED, SCOPE);
        }
        __syncthreads();
    } else {
        if (threadIdx.x == 0) {
            __builtin_amdgcn_fence(__ATOMIC_RELEASE, "agent");
            __hip_atomic_store(slots + (size_t)blockIdx.x * 32, tgt, __ATOMIC_RELAXED, SCOPE);
            unsigned guard = 0;
            while (__hip_atomic_load(gen, __ATOMIC_RELAXED, SCOPE) < tgt) {
                __builtin_amdgcn_s_sleep(8);
                if (++guard > 100000000u) break;
            }
            __builtin_amdgcn_fence(__ATOMIC_ACQUIRE, "agent");
        }
        __syncthreads();
    }
}

// ---------------- generic LDS-tiled transpose: dst[C][R] from src[R][C]
__global__ __launch_bounds__(256) void k_tr(const float* __restrict__ src,
                                            float* __restrict__ dst, int R, int C) {
    __shared__ float tle[32][33];
    int rb = blockIdx.x * 32, cb = blockIdx.y * 32;
    int lr = threadIdx.x & 31, lc = threadIdx.x >> 5;
#pragma unroll
    for (int i = 0; i < 32; i += 8) tle[lc + i][lr] = src[(size_t)(rb + lc + i) * C + cb + lr];
    __syncthreads();
#pragma unroll
    for (int i = 0; i < 32; i += 8) dst[(size_t)(cb + lc + i) * R + rb + lr] = tle[lr][lc + i];
}

// ---------------- WencT[k][dir*1024 + u*4+g]
__global__ __launch_bounds__(256) void k_prep_encw(
    const float* __restrict__ Wih_f, const float* __restrict__ Whh_f,
    const float* __restrict__ Wih_b, const float* __restrict__ Whh_b,
    float* __restrict__ WencT) {
    int idx = blockIdx.x * 256 + threadIdx.x;     // 512*2048
    int k = idx >> 11, col = idx & 2047;
    int dir = col >> 10, cu = col & 1023;
    int u = cu >> 2, g = cu & 3;
    const float* Wih = dir ? Wih_b : Wih_f;
    const float* Whh = dir ? Whh_b : Whh_f;
    float v = (k < 256) ? Wih[(g * H + u) * D + k] : Whh[(g * H + u) * H + (k - 256)];
    WencT[idx] = v;
}

// ---------------- WdT[k][u*4+g]
__global__ __launch_bounds__(256) void k_prep_decw(const float* __restrict__ Wih_d,
                                                   const float* __restrict__ Whh_d,
                                                   float* __restrict__ WdT) {
    int idx = blockIdx.x * 256 + threadIdx.x;     // 1280*2048
    int k = idx >> 11, col = idx & 2047;
    int u = col >> 2, g = col & 3;
    float v = (k < 768) ? Wih_d[(size_t)(g * H2 + u) * 768 + k]
                        : Whh_d[(size_t)(g * H2 + u) * H2 + (k - 768)];
    WdT[idx] = v;
}

// ---------------- final: out = logits - lse[b*T+t]
__global__ __launch_bounds__(256) void k_norm(float* __restrict__ out,
                                              const float* __restrict__ lse) {
    const int total4 = B * T * V / 4;
    int stride = gridDim.x * 256;
    for (int i4 = blockIdx.x * 256 + threadIdx.x; i4 < total4; i4 += stride) {
        int rowv = i4 / (V / 4);
        float l = lse[rowv];
        float4* p = (float4*)out + i4;
        float4 v = *p;
        v.x -= l; v.y -= l; v.z -= l; v.w -= l;
        *p = v;
    }
}

// ==================== THE PERSISTENT KERNEL ====================
__global__ __launch_bounds__(256, 2) void k_seq(
    const int* __restrict__ x, const float* __restrict__ emb_enc,
    const float* __restrict__ emb_dec,
    const float* __restrict__ bih_f, const float* __restrict__ bhh_f,
    const float* __restrict__ bih_b, const float* __restrict__ bhh_b,
    const float* __restrict__ bih_d, const float* __restrict__ bhh_d,
    const float* __restrict__ Wa_e, const float* __restrict__ Wa_h,
    const float* __restrict__ b_a, const float* __restrict__ v_a,
    const float* __restrict__ bout,
    const float* __restrict__ WencT, const float* __restrict__ WdT,
    const float* __restrict__ WoutT, const float* __restrict__ WahT,
    float* __restrict__ enc_out, float* __restrict__ proj_e,
    float* __restrict__ cencT, float* __restrict__ zpenc,
    float* __restrict__ hdecT, float* __restrict__ cdecT,
    float* __restrict__ xcatT, float* __restrict__ q_buf, float* __restrict__ zp_h,
    float* __restrict__ Pm, float* __restrict__ Ps,
    int* __restrict__ Pi, float* __restrict__ lse, float* __restrict__ out,
    int* slots, int* gen) {
    extern __shared__ float xs[];
    const int blk = blockIdx.x, tid = threadIdx.x;
    const int kc = (tid >> 3) & 7;
    const int rp = (tid >> 6) * 8 + (tid & 7);   // 0..31
    int bgen = 0;

    // ===================== ENCODER =====================
    for (int t = 0; t <= T; ++t) {
        if (blk < 128) {
            int rowgrp = blk >> 2, c = (blk >> 1) & 1, bh = blk & 1;
            int dir = rowgrp >> 4;
            // ---- stage
            if (c == 0) {
                if (t < T) {
                    for (int i = tid; i < 4096; i += 256) {
                        int bb = i >> 8, k = i & 255;
                        int tok = x[(bh * 16 + bb) * T + t];
                        xs[k * 20 + bb] = emb_enc[tok * 256 + k];
                    }
                }
            } else {
                if (t == 0) {
                    for (int i = tid; i < 4096; i += 256) {
                        int u = i >> 4, bb = i & 15;
                        xs[u * 20 + bb] = 0.f;
                    }
                } else {
                    bool writer = (rowgrp & 15) == 0;
                    const float* zpp = zpenc + ((t - 1) & 1) * 131072;
                    int pr = t & 1;
                    for (int i = tid; i < 4096; i += 256) {
                        int u = i >> 4, bb = i & 15, bG = bh * 16 + bb;
                        int r = dir * 1024 + u * 4;
                        float z[4];
#pragma unroll
                        for (int g = 0; g < 4; ++g) {
                            float bias = (dir ? bih_b : bih_f)[g * 256 + u] +
                                         (dir ? bhh_b : bhh_f)[g * 256 + u];
                            z[g] = zpp[(size_t)(r + g) * 32 + bG] +
                                   zpp[(size_t)(2048 + r + g) * 32 + bG] + bias;
                        }
                        int ci = ((pr * 2 + dir) * 256 + u) * 32 + bG;
                        float cp = cencT[ci];
                        float c2 = sigf(z[1]) * cp + sigf(z[0]) * ftanh(z[2]);
                        float h2 = sigf(z[3]) * ftanh(c2);
                        xs[u * 20 + bb] = h2;
                        if (writer) {
                            cencT[(((pr ^ 1) * 2 + dir) * 256 + u) * 32 + bG] = c2;
                            enc_out[(size_t)(bG * T + (t - 1)) * H2 + dir * 256 + u] = h2;
                            if (t == T) {
                                hdecT[(dir * 256 + u) * 32 + bG] = h2;
                                cdecT[(dir * 256 + u) * 32 + bG] = c2;
                            }
                        }
                    }
                }
            }
            __syncthreads();
            // ---- mm -> zpenc[t&1][c]
            if (t < T) {
                int r0 = rowgrp * 64 + rp * 2;
                float a0[16], a1[16];
#pragma unroll
                for (int j = 0; j < 16; ++j) { a0[j] = 0.f; a1[j] = 0.f; }
#pragma unroll 4
                for (int j = 0; j < 32; ++j) {
                    int kl = kc + 8 * j;
                    float2 w = *(const float2*)(WencT + (size_t)(c * 256 + kl) * 2048 + r0);
                    const float* xp = xs + kl * 20;
#pragma unroll
                    for (int q = 0; q < 4; ++q) {
                        float4 xv = *(const float4*)(xp + q * 4);
                        a0[q*4+0] = fmaf(w.x, xv.x, a0[q*4+0]); a1[q*4+0] = fmaf(w.y, xv.x, a1[q*4+0]);
                        a0[q*4+1] = fmaf(w.x, xv.y, a0[q*4+1]); a1[q*4+1] = fmaf(w.y, xv.y, a1[q*4+1]);
                        a0[q*4+2] = fmaf(w.x, xv.z, a0[q*4+2]); a1[q*4+2] = fmaf(w.y, xv.z, a1[q*4+2]);
                        a0[q*4+3] = fmaf(w.x, xv.w, a0[q*4+3]); a1[q*4+3] = fmaf(w.y, xv.w, a1[q*4+3]);
                    }
                }
#pragma unroll
                for (int j = 0; j < 16; ++j) {
                    a0[j] += __shfl_xor(a0[j], 8); a0[j] += __shfl_xor(a0[j], 16); a0[j] += __shfl_xor(a0[j], 32);
                    a1[j] += __shfl_xor(a1[j], 8); a1[j] += __shfl_xor(a1[j], 16); a1[j] += __shfl_xor(a1[j], 32);
                }
                if (((tid >> 3) & 7) == 0) {
                    float* zb = zpenc + (t & 1) * 131072 + (size_t)(c * 2048 + r0) * 32 + bh * 16;
#pragma unroll
                    for (int q = 0; q < 4; ++q) {
                        *(float4*)(zb + q * 4)      = make_float4(a0[q*4], a0[q*4+1], a0[q*4+2], a0[q*4+3]);
                        *(float4*)(zb + 32 + q * 4) = make_float4(a1[q*4], a1[q*4+1], a1[q*4+2], a1[q*4+3]);
                    }
                }
            }
        }
        ++bgen; gbar(slots, gen, bgen);
    }

    // ===================== pre-decoder: proj_e + q0 =====================
    {
        if (blk < 256) {
            int r0 = blk * 16;
            for (int i = tid; i < 16 * 512; i += 256) {
                int r = i >> 9, k = i & 511;
                xs[r * 512 + k] = enc_out[(size_t)(r0 + r) * H2 + k];
            }
            __syncthreads();
            int j0 = tid * 2;
            float acc0[16], acc1[16];
#pragma unroll
            for (int r = 0; r < 16; ++r) { acc0[r] = 0.f; acc1[r] = 0.f; }
            const float* w0 = Wa_e + j0 * H2;
            const float* w1 = Wa_e + (j0 + 1) * H2;
            for (int k = 0; k < H2; k += 4) {
                float4 wa = *(const float4*)(w0 + k);
                float4 wb = *(const float4*)(w1 + k);
#pragma unroll
                for (int r = 0; r < 16; ++r) {
                    float4 xv = *(const float4*)(&xs[r * 512 + k]);
                    acc0[r] = fmaf(wa.x, xv.x, acc0[r]); acc0[r] = fmaf(wa.y, xv.y, acc0[r]);
                    acc0[r] = fmaf(wa.z, xv.z, acc0[r]); acc0[r] = fmaf(wa.w, xv.w, acc0[r]);
                    acc1[r] = fmaf(wb.x, xv.x, acc1[r]); acc1[r] = fmaf(wb.y, xv.y, acc1[r]);
                    acc1[r] = fmaf(wb.z, xv.z, acc1[r]); acc1[r] = fmaf(wb.w, xv.w, acc1[r]);
                }
            }
#pragma unroll
            for (int r = 0; r < 16; ++r) {
                float2 st; st.x = acc0[r]; st.y = acc1[r];
                *(float2*)(proj_e + (size_t)(r0 + r) * H2 + j0) = st;
            }
        } else if (blk < 320) {
            int gi = (blk - 256) * 256 + tid;
            int j = gi >> 5, b = gi & 31;
            float a0 = 0, a1 = 0, a2 = 0, a3 = 0;
            const float* wr = Wa_h + (size_t)j * H2;
            for (int k = 0; k < H2; k += 4) {
                float4 w = *(const float4*)(wr + k);
                a0 = fmaf(w.x, hdecT[(k    ) * 32 + b], a0);
                a1 = fmaf(w.y, hdecT[(k + 1) * 32 + b], a1);
                a2 = fmaf(w.z, hdecT[(k + 2) * 32 + b], a2);
                a3 = fmaf(w.w, hdecT[(k + 3) * 32 + b], a3);
            }
            q_buf[b * H2 + j] = (a0 + a1) + (a2 + a3);
        }
    }
    ++bgen; gbar(slots, gen, bgen);

    // ===================== DECODER =====================
    for (int t = 0; t < T; ++t) {
        // ---------- phA: attention pipeline (0..31) || Whh x h_{t-1} (32..287)
        if (blk < 32) {
            int b = blk;
            int tok = SOS;
            if (t > 0) {
                float* rm = xs + S0; float* rs = rm + 256; int* ri = (int*)(rs + 256);
                float m = -INFINITY, s = 0.f; int mi = 0x7fffffff;
                for (int i = tid; i < 512; i += 256) {
                    if (i < 500) {
                        float m2 = Pm[b * 512 + i], s2 = Ps[b * 512 + i];
                        int i2 = Pi[b * 512 + i];
                        if (m2 > m)      { s = s2 + s * __expf(m - m2); m = m2; mi = i2; }
                        else if (m > m2) { s = s + s2 * __expf(m2 - m); }
                        else             { s = s + s2; mi = (mi < i2) ? mi : i2; }
                    }
                }
                rm[tid] = m; rs[tid] = s; ri[tid] = mi;
                __syncthreads();
                for (int off = 128; off >= 1; off >>= 1) {
                    if (tid < off) {
                        float m1 = rm[tid], m2 = rm[tid + off];
                        float s1 = rs[tid], s2 = rs[tid + off];
                        int i1 = ri[tid], i2 = ri[tid + off];
                        float m_, s_; int i_;
                        if (m2 > m1)      { m_ = m2; s_ = s2 + s1 * __expf(m1 - m2); i_ = i2; }
                        else if (m1 > m2) { m_ = m1; s_ = s1 + s2 * __expf(m2 - m1); i_ = i1; }
                        else              { m_ = m1; s_ = s1 + s2; i_ = (i1 < i2) ? i1 : i2; }
                        rm[tid] = m_; rs[tid] = s_; ri[tid] = i_;
                    }
                    __syncthreads();
                }
                if (tid == 0) lse[b * T + (t - 1)] = rm[0] + logf(rs[0]);
                __syncthreads();
                tok = ri[0];
            }
            // embedding -> xcatT rows [0,256)
            xcatT[tid * 32 + b] = emb_dec[tok * 256 + tid];
            // energy -> es (LDS)
            float* es = xs + S0;
            {
                int l = tid & 63, w = tid >> 6;
                float4 qb0 = *(const float4*)(q_buf + b * H2 + l * 8);
                float4 qb1 = *(const float4*)(q_buf + b * H2 + l * 8 + 4);
                float4 ba0 = *(const float4*)(b_a + l * 8);
                float4 ba1 = *(const float4*)(b_a + l * 8 + 4);
                qb0.x += ba0.x; qb0.y += ba0.y; qb0.z += ba0.z; qb0.w += ba0.w;
                qb1.x += ba1.x; qb1.y += ba1.y; qb1.z += ba1.z; qb1.w += ba1.w;
                float4 va0 = *(const float4*)(v_a + l * 8);
                float4 va1 = *(const float4*)(v_a + l * 8 + 4);
                for (int tt = w; tt < T; tt += 4) {
                    const float* pp = proj_e + (size_t)(b * T + tt) * H2 + l * 8;
                    float4 p0 = *(const float4*)(pp);
                    float4 p1 = *(const float4*)(pp + 4);
                    float s = ftanh(p0.x + qb0.x) * va0.x + ftanh(p0.y + qb0.y) * va0.y
                            + ftanh(p0.z + qb0.z) * va0.z + ftanh(p0.w + qb0.w) * va0.w
                            + ftanh(p1.x + qb1.x) * va1.x + ftanh(p1.y + qb1.y) * va1.y
                            + ftanh(p1.z + qb1.z) * va1.z + ftanh(p1.w + qb1.w) * va1.w;
#pragma unroll
                    for (int off = 32; off >= 1; off >>= 1) s += __shfl_xor(s, off);
                    if (l == 0) es[tt] = s;
                }
            }
            __syncthreads();
            // softmax over T=128
            float* red = xs + S0 + 128; float* wsm = xs + S0 + 256;
            if (tid < 128) red[tid] = es[tid];
            __syncthreads();
            for (int off = 64; off >= 1; off >>= 1) {
                if (tid < off) red[tid] = fmaxf(red[tid], red[tid + off]);
                __syncthreads();
            }
            float M = red[0];
            __syncthreads();
            float ev = 0.f;
            if (tid < 128) { ev = __expf(es[tid] - M); red[tid] = ev; }
            __syncthreads();
            for (int off = 64; off >= 1; off >>= 1) {
                if (tid < off) red[tid] += red[tid + off];
                __syncthreads();
            }
            float S = red[0];
            __syncthreads();
            if (tid < 128) wsm[tid] = ev / S;
            __syncthreads();
            // ctx -> xcatT rows [256,768)
            float acc0 = 0.f, acc1 = 0.f;
            const float* eo = enc_out + (size_t)b * T * H2;
#pragma unroll 8
            for (int t2 = 0; t2 < T; ++t2) {
                float wv = wsm[t2];
                acc0 = fmaf(wv, eo[t2 * H2 + tid], acc0);
                acc1 = fmaf(wv, eo[t2 * H2 + tid + 256], acc1);
            }
            xcatT[(256 + tid) * 32 + b] = acc0;
            xcatT[(512 + tid) * 32 + b] = acc1;
        } else if (blk < 288) {
            // Whh_d x h_{t-1}: 2048 rows over 256 blocks (8 rows each, full k)
            int m = blk - 32;
            int rl = tid >> 5, b = tid & 31;
            int col = m * 8 + rl;
            float a0 = 0.f, a1 = 0.f;
            const float* wp = WdT + (size_t)768 * 2048 + col;
            const float* xp = hdecT + b;
#pragma unroll 8
            for (int k = 0; k < 512; k += 2) {
                a0 = fmaf(wp[(size_t)k * 2048], xp[k * 32], a0);
                a1 = fmaf(wp[(size_t)(k + 1) * 2048], xp[(k + 1) * 32], a1);
            }
            zp_h[col * 32 + b] = a0 + a1;
        }
        ++bgen; gbar(slots, gen, bgen);

        // ---------- phB: Wih x xcat (full-k row ownership) + fused cell. all 512 blocks
        {
            int u = blk;                       // one unit per block
            int b = tid & 31, g = (tid >> 5) & 3, kh = tid >> 7;
            int col = u * 4 + g;
            float a0 = 0.f, a1 = 0.f;
            const float* wp = WdT + col;
            const float* xp = xcatT + b;
            int k0 = kh * 384;
#pragma unroll 8
            for (int k = k0; k < k0 + 384; k += 2) {
                a0 = fmaf(wp[(size_t)k * 2048], xp[k * 32], a0);
                a1 = fmaf(wp[(size_t)(k + 1) * 2048], xp[(k + 1) * 32], a1);
            }
            float* zs = xs + S0;
            zs[kh * 128 + g * 32 + b] = a0 + a1;
            __syncthreads();
            if (tid < 32) {
                int bb = tid;
                float z[4];
#pragma unroll
                for (int g2 = 0; g2 < 4; ++g2) {
                    z[g2] = zs[g2 * 32 + bb] + zs[128 + g2 * 32 + bb] +
                            zp_h[(u * 4 + g2) * 32 + bb] +
                            bih_d[g2 * H2 + u] + bhh_d[g2 * H2 + u];
                }
                float cp = cdecT[u * 32 + bb];
                float c2 = sigf(z[1]) * cp + sigf(z[0]) * ftanh(z[2]);
                cdecT[u * 32 + bb] = c2;
                hdecT[u * 32 + bb] = sigf(z[3]) * ftanh(c2);
            }
        }
        ++bgen; gbar(slots, gen, bgen);

        // ---------- phC: logits (0..499) + q piggyback (500..507)
        if (blk < 508) {
            for (int i4 = tid; i4 < 4096; i4 += 256) {
                int k = i4 >> 3, b4 = (i4 & 7) * 4;
                *(float4*)(xs + k * 36 + b4) = *(const float4*)(hdecT + k * 32 + b4);
            }
            __syncthreads();
            bool isQ = (blk >= 500);
            const float* wb = isQ ? (WahT + (blk - 500) * 64) : (WoutT + blk * 64);
            const int wst = isQ ? H2 : V;
            int rp2 = rp * 2;
            float a0[32], a1[32];
#pragma unroll
            for (int j = 0; j < 32; ++j) { a0[j] = 0.f; a1[j] = 0.f; }
#pragma unroll 4
            for (int kk = 0; kk < 64; ++kk) {
                int k = kc + 8 * kk;
                float2 w = *(const float2*)(wb + (size_t)k * wst + rp2);
                const float* xp = xs + k * 36;
#pragma unroll
                for (int q = 0; q < 8; ++q) {
                    float4 xv = *(const float4*)(xp + q * 4);
                    a0[q*4+0] = fmaf(w.x, xv.x, a0[q*4+0]); a1[q*4+0] = fmaf(w.y, xv.x, a1[q*4+0]);
                    a0[q*4+1] = fmaf(w.x, xv.y, a0[q*4+1]); a1[q*4+1] = fmaf(w.y, xv.y, a1[q*4+1]);
                    a0[q*4+2] = fmaf(w.x, xv.z, a0[q*4+2]); a1[q*4+2] = fmaf(w.y, xv.z, a1[q*4+2]);
                    a0[q*4+3] = fmaf(w.x, xv.w, a0[q*4+3]); a1[q*4+3] = fmaf(w.y, xv.w, a1[q*4+3]);
                }
            }
#pragma unroll
            for (int j = 0; j < 32; ++j) {
                a0[j] += __shfl_xor(a0[j], 8); a0[j] += __shfl_xor(a0[j], 16); a0[j] += __shfl_xor(a0[j], 32);
                a1[j] += __shfl_xor(a1[j], 8); a1[j] += __shfl_xor(a1[j], 16); a1[j] += __shfl_xor(a1[j], 32);
            }
            __syncthreads();   // xs reads done; safe to alias z into xs
            if (!isQ) {
                if (((tid >> 3) & 7) == 0) {
#pragma unroll
                    for (int j = 0; j < 32; ++j) {
                        xs[(rp2    ) * 37 + j] = a0[j];
                        xs[(rp2 + 1) * 37 + j] = a1[j];
                    }
                }
                __syncthreads();
                int row0 = blk * 64;
                {
                    int r = tid & 63, bo = tid >> 6;
                    float bv = bout[row0 + r];
#pragma unroll
                    for (int e = 0; e < 8; ++e) {
                        int b = bo * 8 + e;
                        __builtin_nontemporal_store(xs[r * 37 + b] + bv,
                            out + ((size_t)(b * T) + t) * V + row0 + r);
                    }
                }
                float* pm8 = xs + S0; float* ps8 = pm8 + 256; int* pi8 = (int*)(ps8 + 256);
                {
                    int g = tid >> 5, b = tid & 31;
                    float m = -INFINITY, s = 0.f; int mi = 0;
#pragma unroll
                    for (int i = 0; i < 8; ++i) {
                        int rr = g * 8 + i;
                        float v = xs[rr * 37 + b] + bout[row0 + rr];
                        if (v > m) { s *= __expf(m - v); m = v; mi = row0 + rr; }
                        s += __expf(v - m);
                    }
                    pm8[g * 32 + b] = m; ps8[g * 32 + b] = s; pi8[g * 32 + b] = mi;
                }
                __syncthreads();
                if (tid < 32) {
                    int b = tid;
                    float m = pm8[b], s = ps8[b]; int mi = pi8[b];
#pragma unroll
                    for (int g = 1; g < 8; ++g) {
                        float m2 = pm8[g * 32 + b], s2 = ps8[g * 32 + b]; int i2 = pi8[g * 32 + b];
                        if (m2 > m)      { s = s2 + s * __expf(m - m2); m = m2; mi = i2; }
                        else if (m > m2) { s = s + s2 * __expf(m2 - m); }
                        else             { s = s + s2; mi = (mi < i2) ? mi : i2; }
                    }
                    Pm[b * 512 + blk] = m; Ps[b * 512 + blk] = s; Pi[b * 512 + blk] = mi;
                }
            } else {
                if (((tid >> 3) & 7) == 0) {
                    int j0 = (blk - 500) * 64 + rp2;
#pragma unroll
                    for (int b = 0; b < 32; ++b) {
                        q_buf[b * H2 + j0]     = a0[b];
                        q_buf[b * H2 + j0 + 1] = a1[b];
                    }
                }
            }
        }
        ++bgen; gbar(slots, gen, bgen);
    }

    // ---------- tail: lse for t = 127
    if (blk < 32) {
        int b = blk;
        float* rm = xs + S0; float* rs = rm + 256;
        float m = -INFINITY, s = 0.f;
        for (int i = tid; i < 512; i += 256) {
            if (i < 500) {
                float m2 = Pm[b * 512 + i], s2 = Ps[b * 512 + i];
                if (m2 > m)      { s = s2 + s * __expf(m - m2); m = m2; }
                else if (m > m2) { s = s + s2 * __expf(m2 - m); }
                else             { s = s + s2; }
            }
        }
        rm[tid] = m; rs[tid] = s;
        __syncthreads();
        for (int off = 128; off >= 1; off >>= 1) {
            if (tid < off) {
                float m1 = rm[tid], m2 = rm[tid + off];
                float s1 = rs[tid], s2 = rs[tid + off];
                float m_, s_;
                if (m2 > m1)      { m_ = m2; s_ = s2 + s1 * __expf(m1 - m2); }
                else if (m1 > m2) { m_ = m1; s_ = s1 + s2 * __expf(m2 - m1); }
                else              { m_ = m1; s_ = s1 + s2; }
                rm[tid] = m_; rs[tid] = s_;
            }
            __syncthreads();
        }
        if (tid == 0) lse[b * T + (T - 1)] = rm[0] + logf(rs[0]);
    }
}

extern "C" void kernel_launch(void* const* d_in, const int* in_sizes, int n_in,
                              void* d_out, int out_size, void* d_ws, size_t ws_size,
                              hipStream_t stream) {
    const int* x          = (const int*)d_in[0];
    const float* emb_enc  = (const float*)d_in[1];
    const float* Wih_f    = (const float*)d_in[2];
    const float* Whh_f    = (const float*)d_in[3];
    const float* bih_f    = (const float*)d_in[4];
    const float* bhh_f    = (const float*)d_in[5];
    const float* Wih_b    = (const float*)d_in[6];
    const float* Whh_b    = (const float*)d_in[7];
    const float* bih_b    = (const float*)d_in[8];
    const float* bhh_b    = (const float*)d_in[9];
    const float* emb_dec  = (const float*)d_in[10];
    const float* Wa_h     = (const float*)d_in[11];
    const float* Wa_e     = (const float*)d_in[12];
    const float* v_a      = (const float*)d_in[13];
    const float* b_a      = (const float*)d_in[14];
    const float* Wih_d    = (const float*)d_in[15];
    const float* Whh_d    = (const float*)d_in[16];
    const float* bih_d    = (const float*)d_in[17];
    const float* bhh_d    = (const float*)d_in[18];
    const float* Wout     = (const float*)d_in[19];
    const float* bout     = (const float*)d_in[20];
    float* out = (float*)d_out;

    float* ws = (float*)d_ws;
    size_t o = 0;
    float* enc_out = ws + o; o += (size_t)B * T * H2;     // 2,097,152
    float* proj_e  = ws + o; o += (size_t)B * T * H2;     // 2,097,152
    float* WoutT   = ws + o; o += (size_t)H2 * V;         // 16,384,000
    float* WdT     = ws + o; o += (size_t)1280 * 2048;    // 2,621,440
    float* WencT   = ws + o; o += (size_t)512 * 2048;     // 1,048,576
    float* WahT    = ws + o; o += (size_t)H2 * H2;        // 262,144
    float* cencT   = ws + o; o += 2 * 2 * 256 * 32;       // 32,768
    float* zpenc   = ws + o; o += 2 * 2 * 2048 * 32;      // 262,144
    float* hdecT   = ws + o; o += 16384;
    float* cdecT   = ws + o; o += 16384;
    float* xcatT   = ws + o; o += 768 * 32;               // 24,576
    float* q_buf   = ws + o; o += 16384;
    float* zp_h    = ws + o; o += 2048 * 32;              // 65,536
    float* Pm      = ws + o; o += 32 * 512;
    float* Ps      = ws + o; o += 32 * 512;
    float* lse     = ws + o; o += 32 * 128;
    int*   Pi      = (int*)(ws + o); o += 32 * 512;
    int*   slots   = (int*)(ws + o); o += 512 * 32;       // 128B-padded arrival slots
    int*   gen     = (int*)(ws + o); o += 32;

    hipMemsetAsync(cencT, 0, 2 * 2 * 256 * 32 * sizeof(float), stream);
    hipMemsetAsync(slots, 0, (512 * 32 + 32) * sizeof(int), stream);

    k_tr<<<dim3(1000, 16), 256, 0, stream>>>(Wout, WoutT, V, H2);
    k_tr<<<dim3(16, 16), 256, 0, stream>>>(Wa_h, WahT, H2, H2);
    k_prep_encw<<<4096, 256, 0, stream>>>(Wih_f, Whh_f, Wih_b, Whh_b, WencT);
    k_prep_decw<<<10240, 256, 0, stream>>>(Wih_d, Whh_d, WdT);

    k_seq<<<NBLK, NTHR, LDS_FLOATS * sizeof(float), stream>>>(
        x, emb_enc, emb_dec,
        bih_f, bhh_f, bih_b, bhh_b, bih_d, bhh_d,
        Wa_e, Wa_h, b_a, v_a, bout,
        WencT, WdT, WoutT, WahT,
        enc_out, proj_e, cencT, zpenc,
        hdecT, cdecT, xcatT, q_buf, zp_h,
        Pm, Ps, Pi, lse, out, slots, gen);

    k_norm<<<4096, 256, 0, stream>>>(out, lse);
}